// Round 7
// baseline (187.203 us; speedup 1.0000x reference)
//
#include <hip/hip_runtime.h>

// FeatureFinetuningLoss: total = (1/C) * sum_{b,c} max(|m_bc - pos_c + eps| - |m_bc - neg_c + eps| + 1, 0)
// m_bc = mean over 196 spatial elems of (qual[b]==1 ? feat : feat_p)[b,c,:,:]
//
// R7: R6 (nt loads) + rolling software pipeline. 64 channels per single-wave
// block -> 49 FULL-wave nt float4 loads, issued through a depth-8 rolling
// window so vmcnt never drains mid-stream (R6's 13/12 bursts drained the
// queue twice per wave). LDS transpose as before (stride-49 reads: only the
// free 2-way lane aliasing). 2048 blocks, LDS 12.54 KB -> 12 blocks/CU.
// Only the SELECTED tensor per sample is read (~103 MB logical).

#define B_ 128
#define C_ 1024
#define HW_ 196
#define NF4_ 49                       // float4s per channel (784 B)
#define CPB_ 64                       // channels per block (one wave)
#define NF4B_ (CPB_ * NF4_)           // 3136 f4-sums per block
#define NBLOCKS_ (B_ * C_ / CPB_)     // 2048
#define PIPE_ 8                       // rolling-window depth (8 KB in flight)

typedef float v4f __attribute__((ext_vector_type(4)));

__global__ __launch_bounds__(64, 4) void loss_partial_kernel(
    const float* __restrict__ feat, const float* __restrict__ feat_p,
    const float* __restrict__ af, const int* __restrict__ qual,
    const int* __restrict__ label, float* __restrict__ ws)
{
    __shared__ float lsum[NF4B_];          // 12.54 KB
    const int blk  = blockIdx.x;
    const int b    = blk >> 4;             // 16 blocks per sample
    const int c0   = (blk & 15) << 6;      // first channel of this block
    const int lane = threadIdx.x;          // 0..63

    const int q   = qual[b];               // block-uniform -> scalar
    const int lab = label[b];
    const float* sel = (q == 1 ? feat : feat_p);
    const v4f* base = (const v4f*)(sel + ((size_t)b * C_ + c0) * HW_);

    // ---- Phase 1: 49 full-wave nt loads, depth-8 rolling pipeline ----
    v4f t[PIPE_];
    #pragma unroll
    for (int i = 0; i < PIPE_; ++i)
        t[i] = __builtin_nontemporal_load(&base[i * 64 + lane]);
    #pragma unroll
    for (int i = 0; i < NF4_; ++i) {
        const v4f v = t[i & (PIPE_ - 1)];
        if (i + PIPE_ < NF4_)
            t[i & (PIPE_ - 1)] =
                __builtin_nontemporal_load(&base[(i + PIPE_) * 64 + lane]);
        lsum[i * 64 + lane] = (v.x + v.y) + (v.z + v.w);
    }
    __syncthreads();                       // single wave: drains lgkmcnt

    // ---- Phase 2: lane l sums channel l's 49 partials (stride 49: 2-way = free) ----
    const float* my = &lsum[lane * NF4_];
    float a0 = 0.f, a1 = 0.f, a2 = 0.f, a3 = 0.f;
    #pragma unroll
    for (int j = 0; j < 48; j += 4) {
        a0 += my[j]; a1 += my[j + 1]; a2 += my[j + 2]; a3 += my[j + 3];
    }
    const float s = ((a0 + a1) + (a2 + a3)) + my[48];
    const float mean = s * (1.0f / 196.0f);

    const int c = c0 + lane;
    const float pos = af[lab * C_ + c];
    const float neg = af[(1 - lab) * C_ + c];
    float h = fmaxf(fabsf(mean - pos + 1e-6f) - fabsf(mean - neg + 1e-6f) + 1.0f, 0.0f);

    #pragma unroll
    for (int off = 32; off > 0; off >>= 1)
        h += __shfl_xor(h, off, 64);
    if (lane == 0) ws[blk] = h;
}

__global__ __launch_bounds__(256) void final_reduce_kernel(
    const float* __restrict__ ws, float* __restrict__ out)
{
    const int tid = threadIdx.x;
    float s = 0.0f;
    #pragma unroll
    for (int i = 0; i < NBLOCKS_ / 256; ++i)   // 8 loads
        s += ws[tid + i * 256];
    #pragma unroll
    for (int off = 32; off > 0; off >>= 1)
        s += __shfl_xor(s, off, 64);
    __shared__ float sred[4];
    if ((tid & 63) == 0) sred[tid >> 6] = s;
    __syncthreads();
    if (tid == 0)
        out[0] = ((sred[0] + sred[1]) + (sred[2] + sred[3])) * (1.0f / (float)C_);
}

extern "C" void kernel_launch(void* const* d_in, const int* in_sizes, int n_in,
                              void* d_out, int out_size, void* d_ws, size_t ws_size,
                              hipStream_t stream) {
    const float* feat   = (const float*)d_in[0];
    const float* feat_p = (const float*)d_in[1];
    const float* af     = (const float*)d_in[2];   // (2, C)
    const int*   qual   = (const int*)d_in[3];
    const int*   label  = (const int*)d_in[4];
    float* out = (float*)d_out;
    float* ws  = (float*)d_ws;                     // NBLOCKS_ floats = 8 KB

    loss_partial_kernel<<<NBLOCKS_, 64, 0, stream>>>(feat, feat_p, af, qual, label, ws);
    final_reduce_kernel<<<1, 256, 0, stream>>>(ws, out);
}